// Round 1
// baseline (945.123 us; speedup 1.0000x reference)
//
#include <hip/hip_runtime.h>
#include <math.h>

// ---------------------------------------------------------------------------
// Sketched CNN-MNIST forward.
// x (B,1,28,28) -> conv5x5(32) -> pool2 -> relu -> conv5x5(64) -> pool2 -> relu
//   -> flatten (B,1024) -> FC(512)+relu -> FC(10) -> log_softmax
// Weights reconstructed from sketch: w[:, hash_idx] * sgn.
// ---------------------------------------------------------------------------

// ws layout (floats):
//   wc1 : [0, 800)              (32,25)
//   wc2 : [800, 52000)          (64,800)
//   W3  : [52000, 576288)       (512,1024)
//   h2  : [576288, +B*1024)
//   h3  : [.., +B*512)

__global__ __launch_bounds__(256)
void k_reconstruct(const float* __restrict__ w1, const float* __restrict__ w2,
                   const float* __restrict__ w3,
                   const int* __restrict__ hi1, const int* __restrict__ hi2,
                   const int* __restrict__ hi3,
                   const float* __restrict__ s1, const float* __restrict__ s2,
                   const float* __restrict__ s3,
                   float* __restrict__ wc1, float* __restrict__ wc2,
                   float* __restrict__ W3) {
    int i = blockIdx.x * blockDim.x + threadIdx.x;
    if (i < 800) {
        int oc = i / 25, k = i % 25;
        wc1[i] = w1[oc * 128 + hi1[k]] * s1[k];
    } else if (i < 52000) {
        int j = i - 800;
        int oc = j / 800, k = j % 800;
        wc2[j] = w2[oc * 128 + hi2[k]] * s2[k];
    } else if (i < 576288) {
        int j = i - 52000;
        int r = j / 1024, k = j % 1024;
        W3[j] = w3[r * 128 + hi3[k]] * s3[k];
    }
}

// One block per image: conv1+pool+relu (LDS) then conv2+pool+relu -> h2 global.
__global__ __launch_bounds__(256)
void k_conv(const float* __restrict__ x,
            const float* __restrict__ wc1, const float* __restrict__ wc2,
            const float* __restrict__ b1, const float* __restrict__ b2,
            float* __restrict__ h2) {
    __shared__ float s_x[784];       // 28x28 image
    __shared__ float s_w1[800];      // (32,25)
    __shared__ float s_b1[32];
    __shared__ float s_h1[32 * 144]; // (32,12,12) post pool+relu
    __shared__ float s_w2[6400];     // (64, 4ic, 25) chunk

    const int tid = threadIdx.x;
    const int b = blockIdx.x;

    for (int i = tid; i < 784; i += 256) s_x[i] = x[b * 784 + i];
    for (int i = tid; i < 800; i += 256) s_w1[i] = wc1[i];
    if (tid < 32) s_b1[tid] = b1[tid];
    __syncthreads();

    // ---- conv1 (28x28 -> 24x24) + 2x2 maxpool -> 12x12, relu ----
    for (int o = tid; o < 4608; o += 256) {
        int oc = o / 144, pos = o % 144;
        int pi = pos / 12, pj = pos % 12;
        const float* wr = &s_w1[oc * 25];
        float m = -1e30f;
        #pragma unroll
        for (int di = 0; di < 2; di++) {
            #pragma unroll
            for (int dj = 0; dj < 2; dj++) {
                int ci = 2 * pi + di, cj = 2 * pj + dj;
                float sum = 0.f;
                #pragma unroll
                for (int ki = 0; ki < 5; ki++)
                    #pragma unroll
                    for (int kj = 0; kj < 5; kj++)
                        sum += s_x[(ci + ki) * 28 + cj + kj] * wr[ki * 5 + kj];
                m = fmaxf(m, sum);
            }
        }
        s_h1[o] = fmaxf(m + s_b1[oc], 0.f);
    }

    // ---- conv2 (12x12 -> 8x8) + 2x2 maxpool -> 4x4, relu ----
    // each thread owns 4 outputs (o = tid + 256*t), 4 pool pixels each
    float acc[4][4];
    #pragma unroll
    for (int t = 0; t < 4; t++)
        #pragma unroll
        for (int p = 0; p < 4; p++) acc[t][p] = 0.f;

    for (int icb = 0; icb < 8; icb++) {       // input channels in chunks of 4
        __syncthreads();   // conv1 done (icb==0) / prev s_w2 reads done
        for (int i = tid; i < 6400; i += 256) {
            int oc = i / 100, rem = i % 100;
            int ic = rem / 25, kk = rem % 25;
            s_w2[i] = wc2[oc * 800 + (icb * 4 + ic) * 25 + kk];
        }
        __syncthreads();
        #pragma unroll
        for (int t = 0; t < 4; t++) {
            int o = tid + 256 * t;
            int oc = o >> 4, pos = o & 15;
            int pi = pos >> 2, pj = pos & 3;
            #pragma unroll
            for (int p = 0; p < 4; p++) {
                int ci = 2 * pi + (p >> 1), cj = 2 * pj + (p & 1);
                float s = 0.f;
                #pragma unroll
                for (int ic = 0; ic < 4; ic++) {
                    const float* hrow = &s_h1[(icb * 4 + ic) * 144 + ci * 12 + cj];
                    const float* wr = &s_w2[oc * 100 + ic * 25];
                    #pragma unroll
                    for (int ki = 0; ki < 5; ki++)
                        #pragma unroll
                        for (int kj = 0; kj < 5; kj++)
                            s += hrow[ki * 12 + kj] * wr[ki * 5 + kj];
                }
                acc[t][p] += s;
            }
        }
    }

    #pragma unroll
    for (int t = 0; t < 4; t++) {
        int o = tid + 256 * t;
        int oc = o >> 4;
        float m = fmaxf(fmaxf(acc[t][0], acc[t][1]), fmaxf(acc[t][2], acc[t][3]));
        h2[b * 1024 + o] = fmaxf(m + b2[oc], 0.f);
    }
}

// h3 = relu(h2 @ W3^T + b3) : (B,1024)x(512,1024)^T -> (B,512)
__global__ __launch_bounds__(256)
void k_fc1(const float* __restrict__ A, const float* __restrict__ Bw,
           const float* __restrict__ bias, float* __restrict__ C) {
    __shared__ float As[16][17];
    __shared__ float Bs[16][17];
    int tx = threadIdx.x, ty = threadIdx.y;
    int row = blockIdx.y * 16 + ty;       // b
    int colBase = blockIdx.x * 16;        // o
    float acc = 0.f;
    for (int kt = 0; kt < 64; kt++) {
        As[ty][tx] = A[row * 1024 + kt * 16 + tx];
        Bs[ty][tx] = Bw[(colBase + ty) * 1024 + kt * 16 + tx];
        __syncthreads();
        #pragma unroll
        for (int kk = 0; kk < 16; kk++)
            acc += As[ty][kk] * Bs[tx][kk];
        __syncthreads();
    }
    int col = colBase + tx;
    C[row * 512 + col] = fmaxf(acc + bias[col], 0.f);
}

// logits = h3 @ fc2_w^T + fc2_b ; out = log_softmax(logits). One wave/image.
__global__ __launch_bounds__(64)
void k_fc2(const float* __restrict__ h3, const float* __restrict__ w,
           const float* __restrict__ bias, float* __restrict__ out) {
    int b = blockIdx.x, lane = threadIdx.x;
    float acc[10];
    #pragma unroll
    for (int c = 0; c < 10; c++) acc[c] = 0.f;
    for (int k = lane; k < 512; k += 64) {
        float hv = h3[b * 512 + k];
        #pragma unroll
        for (int c = 0; c < 10; c++) acc[c] += hv * w[c * 512 + k];
    }
    #pragma unroll
    for (int c = 0; c < 10; c++)
        #pragma unroll
        for (int off = 32; off >= 1; off >>= 1)
            acc[c] += __shfl_down(acc[c], off);
    if (lane == 0) {
        float l[10], m = -1e30f;
        #pragma unroll
        for (int c = 0; c < 10; c++) { l[c] = acc[c] + bias[c]; m = fmaxf(m, l[c]); }
        float s = 0.f;
        #pragma unroll
        for (int c = 0; c < 10; c++) s += expf(l[c] - m);
        float lse = m + logf(s);
        #pragma unroll
        for (int c = 0; c < 10; c++) out[b * 10 + c] = l[c] - lse;
    }
}

extern "C" void kernel_launch(void* const* d_in, const int* in_sizes, int n_in,
                              void* d_out, int out_size, void* d_ws, size_t ws_size,
                              hipStream_t stream) {
    const float* x    = (const float*)d_in[0];
    const int*   hi1  = (const int*)d_in[1];
    const int*   hi2  = (const int*)d_in[2];
    const int*   hi3  = (const int*)d_in[3];
    const float* s1   = (const float*)d_in[4];
    const float* s2   = (const float*)d_in[5];
    const float* s3   = (const float*)d_in[6];
    const float* w1   = (const float*)d_in[7];
    const float* b1   = (const float*)d_in[8];
    const float* w2   = (const float*)d_in[9];
    const float* b2   = (const float*)d_in[10];
    const float* w3   = (const float*)d_in[11];
    const float* b3   = (const float*)d_in[12];
    const float* fc2w = (const float*)d_in[13];
    const float* fc2b = (const float*)d_in[14];
    float* out = (float*)d_out;

    const int B = in_sizes[0] / 784;   // 4096

    float* ws  = (float*)d_ws;
    float* wc1 = ws;                   // 800
    float* wc2 = ws + 800;             // 51200
    float* W3  = ws + 52000;           // 524288
    float* h2  = ws + 576288;          // B*1024
    float* h3  = h2 + (size_t)B * 1024; // B*512

    k_reconstruct<<<(576288 + 255) / 256, 256, 0, stream>>>(
        w1, w2, w3, hi1, hi2, hi3, s1, s2, s3, wc1, wc2, W3);
    k_conv<<<B, 256, 0, stream>>>(x, wc1, wc2, b1, b2, h2);
    k_fc1<<<dim3(512 / 16, B / 16), dim3(16, 16), 0, stream>>>(h2, W3, b3, h3);
    k_fc2<<<B, 64, 0, stream>>>(h3, fc2w, fc2b, out);
}

// Round 2
// 552.791 us; speedup vs baseline: 1.7097x; 1.7097x over previous
//
#include <hip/hip_runtime.h>
#include <hip/hip_bf16.h>
#include <math.h>

// ---------------------------------------------------------------------------
// Sketched CNN-MNIST forward.
// x (B,1,28,28) -> conv5x5(32) -> pool2 -> relu -> conv5x5(64) -> pool2 -> relu
//   -> flatten (B,1024) -> FC(512)+relu -> FC(10) -> log_softmax
// R1: register-tiled fp32 convs (FMA:LDS ~9:1), fc1 via bf16 MFMA 16x16x32.
// ---------------------------------------------------------------------------

typedef __attribute__((ext_vector_type(8))) short bf16x8;
typedef __attribute__((ext_vector_type(4))) float f32x4;

// ws layout (bytes):
//   wc1  f32   [0,       3200)
//   wc2  f32   [3200,    208000)
//   W3   bf16  [208000,  1256576)
//   h2   bf16  [1256576, 1256576 + B*2048)
//   h3   f32   [.. ,     .. + B*2048)

__global__ __launch_bounds__(256)
void k_reconstruct(const float* __restrict__ w1, const float* __restrict__ w2,
                   const float* __restrict__ w3,
                   const int* __restrict__ hi1, const int* __restrict__ hi2,
                   const int* __restrict__ hi3,
                   const float* __restrict__ s1, const float* __restrict__ s2,
                   const float* __restrict__ s3,
                   float* __restrict__ wc1, float* __restrict__ wc2,
                   __hip_bfloat16* __restrict__ W3) {
    int i = blockIdx.x * blockDim.x + threadIdx.x;
    if (i < 800) {
        int oc = i / 25, k = i % 25;
        wc1[i] = w1[oc * 128 + hi1[k]] * s1[k];
    } else if (i < 52000) {
        int j = i - 800;
        int oc = j / 800, k = j % 800;
        wc2[j] = w2[oc * 128 + hi2[k]] * s2[k];
    } else if (i < 576288) {
        int j = i - 52000;
        int r = j / 1024, k = j % 1024;
        W3[j] = __float2bfloat16(w3[r * 128 + hi3[k]] * s3[k]);
    }
}

// One block per image: conv1+pool+relu (LDS) then conv2+pool+relu -> h2 (bf16).
__global__ __launch_bounds__(256)
void k_conv(const float* __restrict__ x,
            const float* __restrict__ wc1, const float* __restrict__ wc2,
            const float* __restrict__ b1, const float* __restrict__ b2,
            __hip_bfloat16* __restrict__ h2) {
    __shared__ float s_x[784];       // 28x28 image
    __shared__ float s_w1[800];      // (32,25)
    __shared__ float s_b1[32];
    __shared__ float s_h1[32 * 144]; // (32,12,12) post pool+relu
    __shared__ float s_w2[6400];     // (64 oc, 4 ic, 25) chunk

    const int tid = threadIdx.x;
    const int b = blockIdx.x;

    for (int i = tid; i < 784; i += 256) s_x[i] = x[b * 784 + i];
    for (int i = tid; i < 800; i += 256) s_w1[i] = wc1[i];
    if (tid < 32) s_b1[tid] = b1[tid];
    __syncthreads();

    // ---- conv1 (28x28 -> 24x24) + 2x2 maxpool -> 12x12, relu ----
    // 4608 pool outputs, 18 per thread; 6x6 window + 25 weights in registers.
    for (int t = 0; t < 18; ++t) {
        int o = tid + 256 * t;
        int oc = o / 144, pos = o % 144;
        int pi = pos / 12, pj = pos % 12;
        float win[6][6];
        #pragma unroll
        for (int r = 0; r < 6; ++r) {
            const float* rowp = &s_x[(2 * pi + r) * 28 + 2 * pj];
            float2 a = *(const float2*)(rowp);
            float2 c = *(const float2*)(rowp + 2);
            float2 e = *(const float2*)(rowp + 4);
            win[r][0] = a.x; win[r][1] = a.y; win[r][2] = c.x;
            win[r][3] = c.y; win[r][4] = e.x; win[r][5] = e.y;
        }
        const float* wr = &s_w1[oc * 25];
        float w[25];
        #pragma unroll
        for (int k = 0; k < 25; ++k) w[k] = wr[k];
        float m = -1e30f;
        #pragma unroll
        for (int di = 0; di < 2; ++di)
            #pragma unroll
            for (int dj = 0; dj < 2; ++dj) {
                float s = 0.f;
                #pragma unroll
                for (int ki = 0; ki < 5; ++ki)
                    #pragma unroll
                    for (int kj = 0; kj < 5; ++kj)
                        s += win[di + ki][dj + kj] * w[ki * 5 + kj];
                m = fmaxf(m, s);
            }
        s_h1[o] = fmaxf(m + s_b1[oc], 0.f);
    }

    // ---- conv2 (12x12 -> 8x8) + 2x2 maxpool -> 4x4, relu ----
    // thread = (oc = tid>>2, pr = tid&3): conv rows 2pr,2pr+1, all 8 cols.
    const int oc = tid >> 2, pr = tid & 3;
    float acc0[8], acc1[8];
    #pragma unroll
    for (int j = 0; j < 8; ++j) { acc0[j] = 0.f; acc1[j] = 0.f; }

    for (int icb = 0; icb < 8; ++icb) {      // input channels, chunks of 4
        __syncthreads();                      // conv1 done / prev s_w2 reads done
        for (int i = tid; i < 6400; i += 256)
            s_w2[i] = wc2[(i / 100) * 800 + icb * 100 + (i % 100)];
        __syncthreads();
        #pragma unroll
        for (int icl = 0; icl < 4; ++icl) {
            const float* wp = &s_w2[oc * 100 + icl * 25];
            float w[25];
            #pragma unroll
            for (int k = 0; k < 25; ++k) w[k] = wp[k];
            const float* hbase = &s_h1[(icb * 4 + icl) * 144 + (2 * pr) * 12];
            #pragma unroll
            for (int r = 0; r < 6; ++r) {
                float h[12];
                const f32x4* rp = (const f32x4*)(hbase + r * 12);
                f32x4 x0 = rp[0], x1 = rp[1], x2 = rp[2];
                h[0] = x0.x; h[1] = x0.y; h[2] = x0.z; h[3] = x0.w;
                h[4] = x1.x; h[5] = x1.y; h[6] = x1.z; h[7] = x1.w;
                h[8] = x2.x; h[9] = x2.y; h[10] = x2.z; h[11] = x2.w;
                if (r <= 4) {
                    const int ki = r;
                    #pragma unroll
                    for (int j = 0; j < 8; ++j)
                        #pragma unroll
                        for (int kj = 0; kj < 5; ++kj)
                            acc0[j] += h[j + kj] * w[ki * 5 + kj];
                }
                if (r >= 1) {
                    const int ki = r - 1;
                    #pragma unroll
                    for (int j = 0; j < 8; ++j)
                        #pragma unroll
                        for (int kj = 0; kj < 5; ++kj)
                            acc1[j] += h[j + kj] * w[ki * 5 + kj];
                }
            }
        }
    }

    const float bb = b2[oc];
    #pragma unroll
    for (int pc = 0; pc < 4; ++pc) {
        float m = fmaxf(fmaxf(acc0[2 * pc], acc0[2 * pc + 1]),
                        fmaxf(acc1[2 * pc], acc1[2 * pc + 1]));
        h2[(size_t)b * 1024 + oc * 16 + pr * 4 + pc] =
            __float2bfloat16(fmaxf(m + bb, 0.f));
    }
}

// h3 = relu(h2 @ W3^T + b3) via bf16 MFMA 16x16x32.
// A = h2 (B,1024) bf16 row-major; B-op = W3 (512,1024) bf16 row-major.
// A frag: lane holds A[m=lane&15][k = (lane>>4)*8 + j], j=0..7 (contiguous k).
// B frag: lane holds B[k = (lane>>4)*8 + j][n=lane&15] = W3[n][k] (contiguous k).
// D: col(n) = lane&15, row(m) = (lane>>4)*4 + reg.
__global__ __launch_bounds__(256)
void k_fc1_mfma(const __hip_bfloat16* __restrict__ A,
                const __hip_bfloat16* __restrict__ Bw,
                const float* __restrict__ bias, float* __restrict__ C) {
    const int wave = threadIdx.x >> 6;
    const int lane = threadIdx.x & 63;
    const int l15 = lane & 15, quad = lane >> 4;
    const int mBase = blockIdx.y * 64 + wave * 16;
    const int nBase = blockIdx.x * 64;

    f32x4 acc[4];
    #pragma unroll
    for (int nt = 0; nt < 4; ++nt) acc[nt] = (f32x4){0.f, 0.f, 0.f, 0.f};

    const __hip_bfloat16* aP = A + (size_t)(mBase + l15) * 1024 + quad * 8;
    #pragma unroll 4
    for (int kt = 0; kt < 32; ++kt) {
        bf16x8 a = *(const bf16x8*)(aP + kt * 32);
        #pragma unroll
        for (int nt = 0; nt < 4; ++nt) {
            bf16x8 bfr = *(const bf16x8*)(Bw + (size_t)(nBase + nt * 16 + l15) * 1024
                                          + kt * 32 + quad * 8);
            acc[nt] = __builtin_amdgcn_mfma_f32_16x16x32_bf16(a, bfr, acc[nt], 0, 0, 0);
        }
    }

    #pragma unroll
    for (int nt = 0; nt < 4; ++nt) {
        int n = nBase + nt * 16 + l15;
        float bb = bias[n];
        #pragma unroll
        for (int r = 0; r < 4; ++r) {
            int m = mBase + quad * 4 + r;
            C[(size_t)m * 512 + n] = fmaxf(acc[nt][r] + bb, 0.f);
        }
    }
}

// logits = h3 @ fc2_w^T + fc2_b ; out = log_softmax(logits). One wave/image.
__global__ __launch_bounds__(64)
void k_fc2(const float* __restrict__ h3, const float* __restrict__ w,
           const float* __restrict__ bias, float* __restrict__ out) {
    int b = blockIdx.x, lane = threadIdx.x;
    float acc[10];
    #pragma unroll
    for (int c = 0; c < 10; c++) acc[c] = 0.f;
    for (int k = lane; k < 512; k += 64) {
        float hv = h3[b * 512 + k];
        #pragma unroll
        for (int c = 0; c < 10; c++) acc[c] += hv * w[c * 512 + k];
    }
    #pragma unroll
    for (int c = 0; c < 10; c++)
        #pragma unroll
        for (int off = 32; off >= 1; off >>= 1)
            acc[c] += __shfl_down(acc[c], off);
    if (lane == 0) {
        float l[10], m = -1e30f;
        #pragma unroll
        for (int c = 0; c < 10; c++) { l[c] = acc[c] + bias[c]; m = fmaxf(m, l[c]); }
        float s = 0.f;
        #pragma unroll
        for (int c = 0; c < 10; c++) s += expf(l[c] - m);
        float lse = m + logf(s);
        #pragma unroll
        for (int c = 0; c < 10; c++) out[b * 10 + c] = l[c] - lse;
    }
}

extern "C" void kernel_launch(void* const* d_in, const int* in_sizes, int n_in,
                              void* d_out, int out_size, void* d_ws, size_t ws_size,
                              hipStream_t stream) {
    const float* x    = (const float*)d_in[0];
    const int*   hi1  = (const int*)d_in[1];
    const int*   hi2  = (const int*)d_in[2];
    const int*   hi3  = (const int*)d_in[3];
    const float* s1   = (const float*)d_in[4];
    const float* s2   = (const float*)d_in[5];
    const float* s3   = (const float*)d_in[6];
    const float* w1   = (const float*)d_in[7];
    const float* b1   = (const float*)d_in[8];
    const float* w2   = (const float*)d_in[9];
    const float* b2   = (const float*)d_in[10];
    const float* w3   = (const float*)d_in[11];
    const float* b3   = (const float*)d_in[12];
    const float* fc2w = (const float*)d_in[13];
    const float* fc2b = (const float*)d_in[14];
    float* out = (float*)d_out;

    const int B = in_sizes[0] / 784;   // 4096

    char* ws = (char*)d_ws;
    float*          wc1 = (float*)(ws + 0);
    float*          wc2 = (float*)(ws + 3200);
    __hip_bfloat16* W3  = (__hip_bfloat16*)(ws + 208000);
    __hip_bfloat16* h2  = (__hip_bfloat16*)(ws + 1256576);
    float*          h3  = (float*)(ws + 1256576 + (size_t)B * 2048);

    k_reconstruct<<<(576288 + 255) / 256, 256, 0, stream>>>(
        w1, w2, w3, hi1, hi2, hi3, s1, s2, s3, wc1, wc2, W3);
    k_conv<<<B, 256, 0, stream>>>(x, wc1, wc2, b1, b2, h2);
    k_fc1_mfma<<<dim3(512 / 64, B / 64), 256, 0, stream>>>(h2, W3, b3, h3);
    k_fc2<<<B, 64, 0, stream>>>(h3, fc2w, fc2b, out);
}

// Round 3
// 246.391 us; speedup vs baseline: 3.8359x; 2.2436x over previous
//
#include <hip/hip_runtime.h>
#include <hip/hip_bf16.h>
#include <math.h>

// ---------------------------------------------------------------------------
// Sketched CNN-MNIST forward, MFMA everywhere it's matmul-shaped.
// conv1: MFMA, M=576 conv-pos (pool-grouped), N=32 oc, K=25 taps (pad 32)
// conv2: channel-last h1 in LDS; 25 tap-GEMMs with K=ic=32 (no padding)
// fc1  : bf16 MFMA 16x16x32 (R1 kernel)
// ---------------------------------------------------------------------------

typedef __attribute__((ext_vector_type(8))) short bf16x8;
typedef __attribute__((ext_vector_type(4))) float f32x4;

static __device__ inline ushort f2bfu(float v) {
    union { __hip_bfloat16 h; ushort u; } cv;
    cv.h = __float2bfloat16(v);
    return cv.u;
}

// ws layout (bytes):
//   wc1b bf16 [32 oc][32 tap(pad)]      [0,       2048)
//   wc2b bf16 [64 oc][25 tap][32 ic]    [2048,    104448)
//   W3   bf16 [512][1024]               [104448,  1153024)
//   h2   bf16 [B][1024]                 [1153024, +B*2048)
//   h3   f32  [B][512]                  [...,     +B*2048)

__global__ __launch_bounds__(256)
void k_reconstruct(const float* __restrict__ w1, const float* __restrict__ w2,
                   const float* __restrict__ w3,
                   const int* __restrict__ hi1, const int* __restrict__ hi2,
                   const int* __restrict__ hi3,
                   const float* __restrict__ s1, const float* __restrict__ s2,
                   const float* __restrict__ s3,
                   __hip_bfloat16* __restrict__ wc1b,
                   __hip_bfloat16* __restrict__ wc2b,
                   __hip_bfloat16* __restrict__ W3) {
    int i = blockIdx.x * blockDim.x + threadIdx.x;
    if (i < 1024) {
        int oc = i >> 5, k = i & 31;
        float v = (k < 25) ? w1[oc * 128 + hi1[k]] * s1[k] : 0.f;
        wc1b[i] = __float2bfloat16(v);
    } else if (i < 52224) {
        int j = i - 1024;
        int oc = j / 800, r = j % 800;
        int tap = r >> 5, ic = r & 31;
        int f = ic * 25 + tap;                 // original sketch index
        wc2b[j] = __float2bfloat16(w2[oc * 128 + hi2[f]] * s2[f]);
    } else if (i < 576512) {
        int j = i - 52224;
        int r = j >> 10, k = j & 1023;
        W3[j] = __float2bfloat16(w3[r * 128 + hi3[k]] * s3[k]);
    }
}

// One block per image. 4 waves.
__global__ __launch_bounds__(256)
void k_conv(const float* __restrict__ x,
            const __hip_bfloat16* __restrict__ wc1b,
            const __hip_bfloat16* __restrict__ wc2b,
            const float* __restrict__ b1, const float* __restrict__ b2,
            __hip_bfloat16* __restrict__ h2) {
    __shared__ float s_x[784];                       // 28x28 image
    __shared__ __align__(16) ushort s_h1[144 * 32];  // bf16 channel-last [pos][ic]

    const int tid = threadIdx.x;
    const int b = blockIdx.x;
    const int wave = tid >> 6, lane = tid & 63;
    const int l15 = lane & 15, quad = lane >> 4;

    // stage image (float4, coalesced)
    if (tid < 196) ((float4*)s_x)[tid] = ((const float4*)(x + (size_t)b * 784))[tid];

    // conv1 B-fragments + biases (tiny, L2-resident)
    bf16x8 bw1[2];
    float bb1[2];
    #pragma unroll
    for (int nt = 0; nt < 2; ++nt) {
        bw1[nt] = *(const bf16x8*)((const ushort*)wc1b + (nt * 16 + l15) * 32 + quad * 8);
        bb1[nt] = b1[nt * 16 + l15];
    }
    __syncthreads();

    // ---- conv1 via MFMA: M=576 (pool-grouped m-order), N=32, K=32 (25 real) ----
    // m = 16*mt + l15 -> pool block pb = 4*mt + (l15>>2), sub = l15&3 = (di,dj)
    // D rows m = 16*mt + quad*4 + r -> pb_out = 4*mt + quad, pool over r.
    #pragma unroll
    for (int i = 0; i < 9; ++i) {
        const int mt = wave * 9 + i;
        const int pb = 4 * mt + (l15 >> 2);
        const int sub = l15 & 3;
        const int pi = (pb * 171) >> 11;            // pb / 12
        const int pj = pb - pi * 12;
        const int base = (2 * pi + (sub >> 1)) * 28 + 2 * pj + (sub & 1);
        bf16x8 af;
        #pragma unroll
        for (int j = 0; j < 8; ++j) {
            const int tap = quad * 8 + j;
            const int ki = (tap * 205) >> 10;       // tap / 5
            const int kj = tap - ki * 5;
            const int off = (tap < 25) ? (ki * 28 + kj) : 0;
            float v = s_x[base + off];
            v = (tap < 25) ? v : 0.f;
            af[j] = (short)f2bfu(v);
        }
        f32x4 z = {0.f, 0.f, 0.f, 0.f};
        f32x4 c0 = __builtin_amdgcn_mfma_f32_16x16x32_bf16(af, bw1[0], z, 0, 0, 0);
        f32x4 c1 = __builtin_amdgcn_mfma_f32_16x16x32_bf16(af, bw1[1], z, 0, 0, 0);
        const int pbo = 4 * mt + quad;
        float m0 = fmaxf(fmaxf(c0[0], c0[1]), fmaxf(c0[2], c0[3]));
        float m1 = fmaxf(fmaxf(c1[0], c1[1]), fmaxf(c1[2], c1[3]));
        s_h1[pbo * 32 + l15]      = f2bfu(fmaxf(m0 + bb1[0], 0.f));
        s_h1[pbo * 32 + 16 + l15] = f2bfu(fmaxf(m1 + bb1[1], 0.f));
    }
    __syncthreads();

    // ---- conv2: 25 tap-GEMMs, K=ic=32, M=16 pos/wave (pool-grouped), N=64 ----
    // A row m = 16*wave + l15 -> (pr=wave, pc=l15>>2, sub=l15&3)
    const int sub2 = l15 & 3;
    const int ci = 2 * wave + (sub2 >> 1);
    const int cj = 2 * (l15 >> 2) + (sub2 & 1);
    const ushort* aP = &s_h1[(ci * 12 + cj) * 32 + quad * 8];
    const ushort* bP = (const ushort*)wc2b + quad * 8;

    f32x4 acc[4];
    float bb2[4];
    #pragma unroll
    for (int nt = 0; nt < 4; ++nt) {
        acc[nt] = (f32x4){0.f, 0.f, 0.f, 0.f};
        bb2[nt] = b2[nt * 16 + l15];
    }

    #pragma unroll
    for (int tap = 0; tap < 25; ++tap) {
        const int ki = tap / 5, kj = tap % 5;       // compile-time (unrolled)
        bf16x8 a = *(const bf16x8*)(aP + (ki * 12 + kj) * 32);
        #pragma unroll
        for (int nt = 0; nt < 4; ++nt) {
            bf16x8 bf = *(const bf16x8*)(bP + (nt * 16 + l15) * 800 + tap * 32);
            acc[nt] = __builtin_amdgcn_mfma_f32_16x16x32_bf16(a, bf, acc[nt], 0, 0, 0);
        }
    }

    // D rows m = 16*wave + quad*4 + r -> (pr=wave, pc=quad), pool over r
    #pragma unroll
    for (int nt = 0; nt < 4; ++nt) {
        float m = fmaxf(fmaxf(acc[nt][0], acc[nt][1]), fmaxf(acc[nt][2], acc[nt][3]));
        float v = fmaxf(m + bb2[nt], 0.f);
        h2[(size_t)b * 1024 + (nt * 16 + l15) * 16 + wave * 4 + quad] = __float2bfloat16(v);
    }
}

// h3 = relu(h2 @ W3^T + b3) via bf16 MFMA 16x16x32.
__global__ __launch_bounds__(256)
void k_fc1_mfma(const __hip_bfloat16* __restrict__ A,
                const __hip_bfloat16* __restrict__ Bw,
                const float* __restrict__ bias, float* __restrict__ C) {
    const int wave = threadIdx.x >> 6;
    const int lane = threadIdx.x & 63;
    const int l15 = lane & 15, quad = lane >> 4;
    const int mBase = blockIdx.y * 64 + wave * 16;
    const int nBase = blockIdx.x * 64;

    f32x4 acc[4];
    #pragma unroll
    for (int nt = 0; nt < 4; ++nt) acc[nt] = (f32x4){0.f, 0.f, 0.f, 0.f};

    const __hip_bfloat16* aP = A + (size_t)(mBase + l15) * 1024 + quad * 8;
    #pragma unroll 4
    for (int kt = 0; kt < 32; ++kt) {
        bf16x8 a = *(const bf16x8*)(aP + kt * 32);
        #pragma unroll
        for (int nt = 0; nt < 4; ++nt) {
            bf16x8 bfr = *(const bf16x8*)(Bw + (size_t)(nBase + nt * 16 + l15) * 1024
                                          + kt * 32 + quad * 8);
            acc[nt] = __builtin_amdgcn_mfma_f32_16x16x32_bf16(a, bfr, acc[nt], 0, 0, 0);
        }
    }

    #pragma unroll
    for (int nt = 0; nt < 4; ++nt) {
        int n = nBase + nt * 16 + l15;
        float bb = bias[n];
        #pragma unroll
        for (int r = 0; r < 4; ++r) {
            int m = mBase + quad * 4 + r;
            C[(size_t)m * 512 + n] = fmaxf(acc[nt][r] + bb, 0.f);
        }
    }
}

// logits = h3 @ fc2_w^T + fc2_b ; out = log_softmax(logits). One wave/image.
__global__ __launch_bounds__(64)
void k_fc2(const float* __restrict__ h3, const float* __restrict__ w,
           const float* __restrict__ bias, float* __restrict__ out) {
    int b = blockIdx.x, lane = threadIdx.x;
    float acc[10];
    #pragma unroll
    for (int c = 0; c < 10; c++) acc[c] = 0.f;
    for (int k = lane; k < 512; k += 64) {
        float hv = h3[b * 512 + k];
        #pragma unroll
        for (int c = 0; c < 10; c++) acc[c] += hv * w[c * 512 + k];
    }
    #pragma unroll
    for (int c = 0; c < 10; c++)
        #pragma unroll
        for (int off = 32; off >= 1; off >>= 1)
            acc[c] += __shfl_down(acc[c], off);
    if (lane == 0) {
        float l[10], m = -1e30f;
        #pragma unroll
        for (int c = 0; c < 10; c++) { l[c] = acc[c] + bias[c]; m = fmaxf(m, l[c]); }
        float s = 0.f;
        #pragma unroll
        for (int c = 0; c < 10; c++) s += expf(l[c] - m);
        float lse = m + logf(s);
        #pragma unroll
        for (int c = 0; c < 10; c++) out[b * 10 + c] = l[c] - lse;
    }
}

extern "C" void kernel_launch(void* const* d_in, const int* in_sizes, int n_in,
                              void* d_out, int out_size, void* d_ws, size_t ws_size,
                              hipStream_t stream) {
    const float* x    = (const float*)d_in[0];
    const int*   hi1  = (const int*)d_in[1];
    const int*   hi2  = (const int*)d_in[2];
    const int*   hi3  = (const int*)d_in[3];
    const float* s1   = (const float*)d_in[4];
    const float* s2   = (const float*)d_in[5];
    const float* s3   = (const float*)d_in[6];
    const float* w1   = (const float*)d_in[7];
    const float* b1   = (const float*)d_in[8];
    const float* w2   = (const float*)d_in[9];
    const float* b2   = (const float*)d_in[10];
    const float* w3   = (const float*)d_in[11];
    const float* b3   = (const float*)d_in[12];
    const float* fc2w = (const float*)d_in[13];
    const float* fc2b = (const float*)d_in[14];
    float* out = (float*)d_out;

    const int B = in_sizes[0] / 784;   // 4096

    char* ws = (char*)d_ws;
    __hip_bfloat16* wc1b = (__hip_bfloat16*)(ws + 0);
    __hip_bfloat16* wc2b = (__hip_bfloat16*)(ws + 2048);
    __hip_bfloat16* W3   = (__hip_bfloat16*)(ws + 104448);
    __hip_bfloat16* h2   = (__hip_bfloat16*)(ws + 1153024);
    float*          h3   = (float*)(ws + 1153024 + (size_t)B * 2048);

    k_reconstruct<<<(576512 + 255) / 256, 256, 0, stream>>>(
        w1, w2, w3, hi1, hi2, hi3, s1, s2, s3, wc1b, wc2b, W3);
    k_conv<<<B, 256, 0, stream>>>(x, wc1b, wc2b, b1, b2, h2);
    k_fc1_mfma<<<dim3(512 / 64, B / 64), 256, 0, stream>>>(h2, W3, b3, h3);
    k_fc2<<<B, 64, 0, stream>>>(h3, fc2w, fc2b, out);
}

// Round 4
// 208.212 us; speedup vs baseline: 4.5392x; 1.1834x over previous
//
#include <hip/hip_runtime.h>
#include <hip/hip_bf16.h>
#include <math.h>

// ---------------------------------------------------------------------------
// Sketched CNN-MNIST forward, MFMA end-to-end.
// conv1: MFMA, taps laid out t=ki*6+kj (K=30 pad 32) so each A-frag register
//        is one aligned ds_read_b32 (bf16 image + shifted copy in LDS).
// conv2: channel-last h1 (stride-40 swizzle), 25 tap-GEMMs K=ic=32,
//        4 images/block -> B-fragments reused 4x from registers.
// fc1+fc2+log_softmax fused: 16 rows/block, h3 in LDS, never hits HBM.
// ---------------------------------------------------------------------------

typedef __attribute__((ext_vector_type(8))) short bf16x8;
typedef __attribute__((ext_vector_type(4))) float f32x4;

static __device__ inline ushort f2bfu(float v) {
    union { __hip_bfloat16 h; ushort u; } cv;
    cv.h = __float2bfloat16(v);
    return cv.u;
}

// ws layout (bytes):
//   wc1b bf16 [32 oc][32 t]  t=ki*6+kj   [0,       2048)
//   wc2b bf16 [64 oc][25 tap][32 ic]     [2048,    104448)
//   W3   bf16 [512][1024]                [104448,  1153024)
//   h2   bf16 [B][1024]                  [1153024, +B*2048)

__global__ __launch_bounds__(256)
void k_reconstruct(const float* __restrict__ w1, const float* __restrict__ w2,
                   const float* __restrict__ w3,
                   const int* __restrict__ hi1, const int* __restrict__ hi2,
                   const int* __restrict__ hi3,
                   const float* __restrict__ s1, const float* __restrict__ s2,
                   const float* __restrict__ s3,
                   __hip_bfloat16* __restrict__ wc1b,
                   __hip_bfloat16* __restrict__ wc2b,
                   __hip_bfloat16* __restrict__ W3) {
    int i = blockIdx.x * blockDim.x + threadIdx.x;
    if (i < 1024) {
        int oc = i >> 5, t = i & 31;
        int ki = (t * 43) >> 8;            // t / 6
        int kj = t - 6 * ki;
        float v = 0.f;
        if (ki < 5 && kj < 5) {
            int f = ki * 5 + kj;
            v = w1[oc * 128 + hi1[f]] * s1[f];
        }
        wc1b[i] = __float2bfloat16(v);
    } else if (i < 52224) {
        int j = i - 1024;
        int oc = j / 800, r = j % 800;
        int tap = r >> 5, ic = r & 31;
        int f = ic * 25 + tap;             // original sketch index
        wc2b[j] = __float2bfloat16(w2[oc * 128 + hi2[f]] * s2[f]);
    } else if (i < 576512) {
        int j = i - 52224;
        int r = j >> 10, k = j & 1023;
        W3[j] = __float2bfloat16(w3[r * 128 + hi3[k]] * s3[k]);
    }
}

// 4 images per block, 4 waves (wave = image for conv1, = pool-row for conv2).
__global__ __launch_bounds__(256)
void k_conv(const float* __restrict__ x,
            const __hip_bfloat16* __restrict__ wc1b,
            const __hip_bfloat16* __restrict__ wc2b,
            const float* __restrict__ b1, const float* __restrict__ b2,
            __hip_bfloat16* __restrict__ h2) {
    __shared__ __align__(16) ushort s_xb[4 * 816];        // bf16 images (+pad)
    __shared__ __align__(16) ushort s_sh[4 * 816];        // shifted by 1 elem
    __shared__ __align__(16) ushort s_h1[4 * 144 * 40];   // [img][pos][ic] stride 40

    const int tid = threadIdx.x;
    const int b0 = blockIdx.x * 4;
    const int wave = tid >> 6, lane = tid & 63;
    const int l15 = lane & 15, quad = lane >> 4;

    // ---- stage 4 images as bf16 (coalesced float4) ----
    {
        const float4* xg = (const float4*)(x + (size_t)b0 * 784);
        for (int i = tid; i < 784; i += 256) {
            float4 v = xg[i];
            int img = i / 196;
            int pos = (i - img * 196) * 4;
            ushort* dst = &s_xb[img * 816 + pos];
            dst[0] = f2bfu(v.x); dst[1] = f2bfu(v.y);
            dst[2] = f2bfu(v.z); dst[3] = f2bfu(v.w);
        }
        if (tid < 128) {                    // zero the pad (MFMA reads it x0 weight)
            int img = tid >> 5, p = 784 + (tid & 31);
            s_xb[img * 816 + p] = 0;
        }
    }

    // conv1 B-fragments + biases (tiny, L2-resident)
    bf16x8 bw1[2];
    float bb1[2];
    #pragma unroll
    for (int nt = 0; nt < 2; ++nt) {
        bw1[nt] = *(const bf16x8*)((const ushort*)wc1b + (nt * 16 + l15) * 32 + quad * 8);
        bb1[nt] = b1[nt * 16 + l15];
    }
    __syncthreads();

    // shifted copy: s_sh[p] = s_xb[p+1]
    #pragma unroll
    for (int img = 0; img < 4; ++img)
        for (int p = tid; p < 816; p += 256)
            s_sh[img * 816 + p] = (p < 815) ? s_xb[img * 816 + p + 1] : (ushort)0;
    __syncthreads();

    // ---- conv1 via MFMA: wave = image. M=576 pool-grouped, N=32, K=32(30) ----
    // tap t = ki*6+kj; register r holds taps (q8+2r, q8+2r+1) = same-row adjacent
    // pixels -> one aligned ds_read_b32 (odd-col lanes use the shifted copy).
    const int sub = l15 & 3;
    const bool oddc = (sub & 1) != 0;
    const ushort* srcImg = (oddc ? s_sh : s_xb) + wave * 816;
    int offr[4];
    #pragma unroll
    for (int r = 0; r < 4; ++r) {
        int t = quad * 8 + 2 * r;          // even
        int row = (t * 43) >> 8;           // t / 6
        int col = t - 6 * row;             // even
        offr[r] = row * 28 + col;          // even
    }
    #pragma unroll
    for (int i = 0; i < 36; ++i) {
        const int pb = 4 * i + (l15 >> 2);
        const int pi = (pb * 171) >> 11;   // pb / 12
        const int pj = pb - 12 * pi;
        int base = (2 * pi + (sub >> 1)) * 28 + 2 * pj + (sub & 1) - (oddc ? 1 : 0);
        const ushort* p0 = srcImg + base;  // even element index: b32-aligned
        union { bf16x8 v; uint u[4]; } A;
        A.u[0] = *(const uint*)(p0 + offr[0]);
        A.u[1] = *(const uint*)(p0 + offr[1]);
        A.u[2] = *(const uint*)(p0 + offr[2]);
        A.u[3] = *(const uint*)(p0 + offr[3]);
        f32x4 z = {0.f, 0.f, 0.f, 0.f};
        f32x4 c0 = __builtin_amdgcn_mfma_f32_16x16x32_bf16(A.v, bw1[0], z, 0, 0, 0);
        f32x4 c1 = __builtin_amdgcn_mfma_f32_16x16x32_bf16(A.v, bw1[1], z, 0, 0, 0);
        const int pbo = 4 * i + quad;
        float m0 = fmaxf(fmaxf(c0[0], c0[1]), fmaxf(c0[2], c0[3]));
        float m1 = fmaxf(fmaxf(c1[0], c1[1]), fmaxf(c1[2], c1[3]));
        s_h1[(wave * 144 + pbo) * 40 + l15]      = f2bfu(fmaxf(m0 + bb1[0], 0.f));
        s_h1[(wave * 144 + pbo) * 40 + 16 + l15] = f2bfu(fmaxf(m1 + bb1[1], 0.f));
    }
    __syncthreads();

    // ---- conv2: 25 tap-GEMMs, K=ic=32, wave = pool-row slice, 4 images ----
    const int sub2 = l15 & 3;
    const int ci2 = 2 * wave + (sub2 >> 1);
    const int cj2 = 2 * (l15 >> 2) + (sub2 & 1);
    const int apos = (ci2 * 12 + cj2) * 40 + quad * 8;
    const ushort* bP = (const ushort*)wc2b + quad * 8;

    f32x4 acc[4][4];                       // [img][nt]
    float bb2[4];
    #pragma unroll
    for (int nt = 0; nt < 4; ++nt) {
        bb2[nt] = b2[nt * 16 + l15];
        #pragma unroll
        for (int img = 0; img < 4; ++img)
            acc[img][nt] = (f32x4){0.f, 0.f, 0.f, 0.f};
    }

    #pragma unroll
    for (int tap = 0; tap < 25; ++tap) {
        const int ki = tap / 5, kj = tap % 5;          // compile-time
        bf16x8 a[4];
        #pragma unroll
        for (int img = 0; img < 4; ++img)
            a[img] = *(const bf16x8*)&s_h1[img * 5760 + apos + (ki * 12 + kj) * 40];
        #pragma unroll
        for (int nt = 0; nt < 4; ++nt) {
            bf16x8 bf = *(const bf16x8*)(bP + (nt * 16 + l15) * 800 + tap * 32);
            #pragma unroll
            for (int img = 0; img < 4; ++img)
                acc[img][nt] = __builtin_amdgcn_mfma_f32_16x16x32_bf16(
                    a[img], bf, acc[img][nt], 0, 0, 0);
        }
    }

    // D rows m = quad*4+r -> (pool row = wave, pool col = quad), max over r
    #pragma unroll
    for (int img = 0; img < 4; ++img)
        #pragma unroll
        for (int nt = 0; nt < 4; ++nt) {
            f32x4 c = acc[img][nt];
            float m = fmaxf(fmaxf(c[0], c[1]), fmaxf(c[2], c[3]));
            float v = fmaxf(m + bb2[nt], 0.f);
            h2[(size_t)(b0 + img) * 1024 + (nt * 16 + l15) * 16 + wave * 4 + quad] =
                __float2bfloat16(v);
        }
}

// Fused fc1 (bf16 MFMA) + fc2 + log_softmax. Block = 16 images, grid = B/16.
__global__ __launch_bounds__(256)
void k_fc(const __hip_bfloat16* __restrict__ A, const __hip_bfloat16* __restrict__ Bw,
          const float* __restrict__ b3, const float* __restrict__ fc2w,
          const float* __restrict__ fc2b, float* __restrict__ out) {
    __shared__ float s_h3[16 * 516];       // padded stride vs bank conflicts
    __shared__ float s_lg[16 * 10];

    const int tid = threadIdx.x;
    const int wave = tid >> 6, lane = tid & 63;
    const int l15 = lane & 15, quad = lane >> 4;
    const int mBase = blockIdx.x * 16;
    const int nBase = wave * 128;

    f32x4 acc[8];
    #pragma unroll
    for (int nt = 0; nt < 8; ++nt) acc[nt] = (f32x4){0.f, 0.f, 0.f, 0.f};

    const __hip_bfloat16* aP = A + (size_t)(mBase + l15) * 1024 + quad * 8;
    const __hip_bfloat16* bP = Bw + (size_t)(nBase + l15) * 1024 + quad * 8;
    #pragma unroll 4
    for (int kt = 0; kt < 32; ++kt) {
        bf16x8 a = *(const bf16x8*)(aP + kt * 32);
        #pragma unroll
        for (int nt = 0; nt < 8; ++nt) {
            bf16x8 b = *(const bf16x8*)(bP + (size_t)nt * 16 * 1024 + kt * 32);
            acc[nt] = __builtin_amdgcn_mfma_f32_16x16x32_bf16(a, b, acc[nt], 0, 0, 0);
        }
    }

    #pragma unroll
    for (int nt = 0; nt < 8; ++nt) {
        int col = nBase + nt * 16 + l15;
        float bb = b3[col];
        #pragma unroll
        for (int r = 0; r < 4; ++r)
            s_h3[(quad * 4 + r) * 516 + col] = fmaxf(acc[nt][r] + bb, 0.f);
    }
    __syncthreads();

    if (tid < 160) {                        // (m, c) dot products, float4
        int m = tid / 10, c = tid - 10 * m;
        const float4* wv = (const float4*)(fc2w + c * 512);
        const float4* hv = (const float4*)&s_h3[m * 516];
        float s = 0.f;
        #pragma unroll 4
        for (int k = 0; k < 128; ++k) {
            float4 h = hv[k], w = wv[k];
            s += h.x * w.x + h.y * w.y + h.z * w.z + h.w * w.w;
        }
        s_lg[m * 10 + c] = s + fc2b[c];
    }
    __syncthreads();

    if (tid < 16) {
        int m = tid;
        float mx = -1e30f;
        #pragma unroll
        for (int c = 0; c < 10; ++c) mx = fmaxf(mx, s_lg[m * 10 + c]);
        float sum = 0.f;
        #pragma unroll
        for (int c = 0; c < 10; ++c) sum += expf(s_lg[m * 10 + c] - mx);
        float lse = mx + logf(sum);
        #pragma unroll
        for (int c = 0; c < 10; ++c)
            out[(size_t)(mBase + m) * 10 + c] = s_lg[m * 10 + c] - lse;
    }
}

extern "C" void kernel_launch(void* const* d_in, const int* in_sizes, int n_in,
                              void* d_out, int out_size, void* d_ws, size_t ws_size,
                              hipStream_t stream) {
    const float* x    = (const float*)d_in[0];
    const int*   hi1  = (const int*)d_in[1];
    const int*   hi2  = (const int*)d_in[2];
    const int*   hi3  = (const int*)d_in[3];
    const float* s1   = (const float*)d_in[4];
    const float* s2   = (const float*)d_in[5];
    const float* s3   = (const float*)d_in[6];
    const float* w1   = (const float*)d_in[7];
    const float* b1   = (const float*)d_in[8];
    const float* w2   = (const float*)d_in[9];
    const float* b2   = (const float*)d_in[10];
    const float* w3   = (const float*)d_in[11];
    const float* b3   = (const float*)d_in[12];
    const float* fc2w = (const float*)d_in[13];
    const float* fc2b = (const float*)d_in[14];
    float* out = (float*)d_out;

    const int B = in_sizes[0] / 784;   // 4096

    char* ws = (char*)d_ws;
    __hip_bfloat16* wc1b = (__hip_bfloat16*)(ws + 0);
    __hip_bfloat16* wc2b = (__hip_bfloat16*)(ws + 2048);
    __hip_bfloat16* W3   = (__hip_bfloat16*)(ws + 104448);
    __hip_bfloat16* h2   = (__hip_bfloat16*)(ws + 1153024);

    k_reconstruct<<<(576512 + 255) / 256, 256, 0, stream>>>(
        w1, w2, w3, hi1, hi2, hi3, s1, s2, s3, wc1b, wc2b, W3);
    k_conv<<<B / 4, 256, 0, stream>>>(x, wc1b, wc2b, b1, b2, h2);
    k_fc<<<B / 16, 256, 0, stream>>>(h2, W3, b3, fc2w, fc2b, out);
}

// Round 5
// 171.193 us; speedup vs baseline: 5.5208x; 1.2162x over previous
//
#include <hip/hip_runtime.h>
#include <hip/hip_bf16.h>
#include <math.h>

// ---------------------------------------------------------------------------
// Sketched CNN-MNIST forward, MFMA end-to-end.
// conv1: MFMA, taps t=ki*6+kj (K=30 pad 32); A-frag = 4 aligned ds_read_b32
//        (bf16 image + 1-shifted copy, built during staging).
// conv2: channel-last h1 (stride-40), 25 tap-GEMMs K=ic=32, 4 img/block;
//        8 waves = (pool-row, n-half) for 2x the latency hiding of R4.
// fc1:   1024-thr blocks, 16 waves x 32 cols, A-tile staged in LDS;
//        fc2 + log_softmax fused in the same block.
// ---------------------------------------------------------------------------

typedef __attribute__((ext_vector_type(8))) short bf16x8;
typedef __attribute__((ext_vector_type(4))) float f32x4;

static __device__ inline ushort f2bfu(float v) {
    union { __hip_bfloat16 h; ushort u; } cv;
    cv.h = __float2bfloat16(v);
    return cv.u;
}

// ws layout (bytes):
//   wc1b bf16 [32 oc][32 t]  t=ki*6+kj   [0,       2048)
//   wc2b bf16 [64 oc][25 tap][32 ic]     [2048,    104448)
//   W3   bf16 [512][1024]                [104448,  1153024)
//   h2   bf16 [B][1024]                  [1153024, +B*2048)

__global__ __launch_bounds__(256)
void k_reconstruct(const float* __restrict__ w1, const float* __restrict__ w2,
                   const float* __restrict__ w3,
                   const int* __restrict__ hi1, const int* __restrict__ hi2,
                   const int* __restrict__ hi3,
                   const float* __restrict__ s1, const float* __restrict__ s2,
                   const float* __restrict__ s3,
                   __hip_bfloat16* __restrict__ wc1b,
                   __hip_bfloat16* __restrict__ wc2b,
                   __hip_bfloat16* __restrict__ W3) {
    int i = blockIdx.x * blockDim.x + threadIdx.x;
    if (i < 1024) {
        int oc = i >> 5, t = i & 31;
        int ki = (t * 43) >> 8;            // t / 6
        int kj = t - 6 * ki;
        float v = 0.f;
        if (ki < 5 && kj < 5) {
            int f = ki * 5 + kj;
            v = w1[oc * 128 + hi1[f]] * s1[f];
        }
        wc1b[i] = __float2bfloat16(v);
    } else if (i < 52224) {
        int j = i - 1024;
        int oc = j / 800, r = j % 800;
        int tap = r >> 5, ic = r & 31;
        int f = ic * 25 + tap;             // original sketch index
        wc2b[j] = __float2bfloat16(w2[oc * 128 + hi2[f]] * s2[f]);
    } else if (i < 576512) {
        int j = i - 52224;
        int r = j >> 10, k = j & 1023;
        W3[j] = __float2bfloat16(w3[r * 128 + hi3[k]] * s3[k]);
    }
}

// 4 images per block, 8 waves.
// conv1: wave = (img, half) -> 18 m-tiles. conv2: wave = (pool-row, n-half).
__global__ __launch_bounds__(512)
void k_conv(const float* __restrict__ x,
            const __hip_bfloat16* __restrict__ wc1b,
            const __hip_bfloat16* __restrict__ wc2b,
            const float* __restrict__ b1, const float* __restrict__ b2,
            __hip_bfloat16* __restrict__ h2) {
    __shared__ __align__(16) ushort s_xb[4 * 816];        // bf16 images (+pad)
    __shared__ __align__(16) ushort s_sh[4 * 816];        // shifted by 1 elem
    __shared__ __align__(16) ushort s_h1[4 * 144 * 40];   // [img][pos][ic] stride 40

    const int tid = threadIdx.x;
    const int b0 = blockIdx.x * 4;
    const int wave = tid >> 6, lane = tid & 63;
    const int l15 = lane & 15, quad = lane >> 4;

    // ---- stage 4 images as bf16; build the shifted copy in the same pass ----
    {
        const float4* xg = (const float4*)(x + (size_t)b0 * 784);
        for (int i = tid; i < 784; i += 512) {
            float4 v = xg[i];
            int img = i / 196;
            int pos = (i - img * 196) * 4;
            ushort u0 = f2bfu(v.x), u1 = f2bfu(v.y), u2 = f2bfu(v.z), u3 = f2bfu(v.w);
            ushort* dst = &s_xb[img * 816 + pos];
            dst[0] = u0; dst[1] = u1; dst[2] = u2; dst[3] = u3;
            ushort* ds = &s_sh[img * 816 + pos];
            if (pos > 0) ds[-1] = u0;
            ds[0] = u1; ds[1] = u2; ds[2] = u3;
        }
        for (int j = tid; j < 4 * 33; j += 512) {   // zero pads
            int img = j / 33, k = j - 33 * (j / 33);
            s_sh[img * 816 + 783 + k] = 0;
            if (k < 32) s_xb[img * 816 + 784 + k] = 0;
        }
    }

    // conv1 B-fragments + biases (tiny, L2-resident)
    bf16x8 bw1[2];
    float bb1[2];
    #pragma unroll
    for (int nt = 0; nt < 2; ++nt) {
        bw1[nt] = *(const bf16x8*)((const ushort*)wc1b + (nt * 16 + l15) * 32 + quad * 8);
        bb1[nt] = b1[nt * 16 + l15];
    }
    __syncthreads();

    // ---- conv1 via MFMA: M=576 pool-grouped per image, N=32, K=32(30) ----
    {
        const int img = wave >> 1, half = wave & 1;
        const int sub = l15 & 3;
        const bool oddc = (sub & 1) != 0;
        const ushort* srcImg = (oddc ? s_sh : s_xb) + img * 816;
        int offr[4];
        #pragma unroll
        for (int r = 0; r < 4; ++r) {
            int t = quad * 8 + 2 * r;          // even
            int row = (t * 43) >> 8;           // t / 6
            int col = t - 6 * row;             // even
            offr[r] = row * 28 + col;          // even
        }
        #pragma unroll
        for (int ii = 0; ii < 18; ++ii) {
            const int i = half * 18 + ii;
            const int pb = 4 * i + (l15 >> 2);
            const int pi = (pb * 171) >> 11;   // pb / 12
            const int pj = pb - 12 * pi;
            int base = (2 * pi + (sub >> 1)) * 28 + 2 * pj + (sub & 1) - (oddc ? 1 : 0);
            const ushort* p0 = srcImg + base;  // even elem index: b32-aligned
            union { bf16x8 v; uint u[4]; } A;
            A.u[0] = *(const uint*)(p0 + offr[0]);
            A.u[1] = *(const uint*)(p0 + offr[1]);
            A.u[2] = *(const uint*)(p0 + offr[2]);
            A.u[3] = *(const uint*)(p0 + offr[3]);
            f32x4 z = {0.f, 0.f, 0.f, 0.f};
            f32x4 c0 = __builtin_amdgcn_mfma_f32_16x16x32_bf16(A.v, bw1[0], z, 0, 0, 0);
            f32x4 c1 = __builtin_amdgcn_mfma_f32_16x16x32_bf16(A.v, bw1[1], z, 0, 0, 0);
            const int pbo = 4 * i + quad;
            float m0 = fmaxf(fmaxf(c0[0], c0[1]), fmaxf(c0[2], c0[3]));
            float m1 = fmaxf(fmaxf(c1[0], c1[1]), fmaxf(c1[2], c1[3]));
            s_h1[(img * 144 + pbo) * 40 + l15]      = f2bfu(fmaxf(m0 + bb1[0], 0.f));
            s_h1[(img * 144 + pbo) * 40 + 16 + l15] = f2bfu(fmaxf(m1 + bb1[1], 0.f));
        }
    }
    __syncthreads();

    // ---- conv2: 25 tap-GEMMs, K=ic=32; wave = (pool-row, n-half), 4 images ----
    const int pr = wave >> 1, nh = wave & 1;
    const int sub2 = l15 & 3;
    const int ci2 = 2 * pr + (sub2 >> 1);
    const int cj2 = 2 * (l15 >> 2) + (sub2 & 1);
    const int apos = (ci2 * 12 + cj2) * 40 + quad * 8;
    const ushort* bP = (const ushort*)wc2b + quad * 8;

    f32x4 acc[4][2];                       // [img][ntl]
    float bb2[2];
    #pragma unroll
    for (int ntl = 0; ntl < 2; ++ntl) {
        bb2[ntl] = b2[(nh * 2 + ntl) * 16 + l15];
        #pragma unroll
        for (int img = 0; img < 4; ++img)
            acc[img][ntl] = (f32x4){0.f, 0.f, 0.f, 0.f};
    }

    #pragma unroll
    for (int tap = 0; tap < 25; ++tap) {
        const int ki = tap / 5, kj = tap % 5;          // compile-time
        bf16x8 a[4];
        #pragma unroll
        for (int img = 0; img < 4; ++img)
            a[img] = *(const bf16x8*)&s_h1[img * 5760 + apos + (ki * 12 + kj) * 40];
        #pragma unroll
        for (int ntl = 0; ntl < 2; ++ntl) {
            bf16x8 bf = *(const bf16x8*)(bP + ((nh * 2 + ntl) * 16 + l15) * 800 + tap * 32);
            #pragma unroll
            for (int img = 0; img < 4; ++img)
                acc[img][ntl] = __builtin_amdgcn_mfma_f32_16x16x32_bf16(
                    a[img], bf, acc[img][ntl], 0, 0, 0);
        }
    }

    // D rows m = quad*4+r -> (pool row = pr, pool col = quad), max over r
    #pragma unroll
    for (int img = 0; img < 4; ++img)
        #pragma unroll
        for (int ntl = 0; ntl < 2; ++ntl) {
            f32x4 c = acc[img][ntl];
            float m = fmaxf(fmaxf(c[0], c[1]), fmaxf(c[2], c[3]));
            float v = fmaxf(m + bb2[ntl], 0.f);
            h2[(size_t)(b0 + img) * 1024 + ((nh * 2 + ntl) * 16 + l15) * 16 + pr * 4 + quad] =
                __float2bfloat16(v);
        }
}

// Fused fc1 (bf16 MFMA) + fc2 + log_softmax.
// Block = 1024 threads = 16 waves; 16 images x 512 cols; wave = 32-col strip.
__global__ __launch_bounds__(1024)
void k_fc(const __hip_bfloat16* __restrict__ A, const __hip_bfloat16* __restrict__ Bw,
          const float* __restrict__ b3, const float* __restrict__ fc2w,
          const float* __restrict__ fc2b, float* __restrict__ out) {
    __shared__ __align__(16) ushort s_A[16 * 1032];   // A tile, +8 pad per row
    __shared__ float s_h3[16 * 516];
    __shared__ float s_lg[16 * 10];

    const int tid = threadIdx.x;
    const int wave = tid >> 6, lane = tid & 63;
    const int l15 = lane & 15, quad = lane >> 4;
    const int mBase = blockIdx.x * 16;
    const int nBase = wave * 32;

    // stage A row `wave` into LDS (64 lanes x 32 B = 2 KB row)
    {
        const uint4* g = (const uint4*)(A + (size_t)(mBase + wave) * 1024);
        uint4 v0 = g[lane * 2], v1 = g[lane * 2 + 1];
        uint4* d = (uint4*)&s_A[wave * 1032 + lane * 16];
        d[0] = v0; d[1] = v1;
    }
    __syncthreads();

    f32x4 acc[2];
    acc[0] = (f32x4){0.f, 0.f, 0.f, 0.f};
    acc[1] = (f32x4){0.f, 0.f, 0.f, 0.f};

    const ushort* aP = &s_A[l15 * 1032 + quad * 8];
    const __hip_bfloat16* bP = Bw + (size_t)(nBase + l15) * 1024 + quad * 8;
    #pragma unroll 4
    for (int kt = 0; kt < 32; ++kt) {
        bf16x8 a = *(const bf16x8*)(aP + kt * 32);
        #pragma unroll
        for (int ntl = 0; ntl < 2; ++ntl) {
            bf16x8 b = *(const bf16x8*)(bP + (size_t)ntl * 16 * 1024 + kt * 32);
            acc[ntl] = __builtin_amdgcn_mfma_f32_16x16x32_bf16(a, b, acc[ntl], 0, 0, 0);
        }
    }

    #pragma unroll
    for (int ntl = 0; ntl < 2; ++ntl) {
        int col = nBase + ntl * 16 + l15;
        float bb = b3[col];
        #pragma unroll
        for (int r = 0; r < 4; ++r)
            s_h3[(quad * 4 + r) * 516 + col] = fmaxf(acc[ntl][r] + bb, 0.f);
    }
    __syncthreads();

    if (tid < 160) {                        // (m, c) dot products, float4
        int m = tid / 10, c = tid - 10 * (tid / 10);
        const float4* wv = (const float4*)(fc2w + c * 512);
        const float4* hv = (const float4*)&s_h3[m * 516];
        float s = 0.f;
        #pragma unroll 4
        for (int k = 0; k < 128; ++k) {
            float4 h = hv[k], w = wv[k];
            s += h.x * w.x + h.y * w.y + h.z * w.z + h.w * w.w;
        }
        s_lg[m * 10 + c] = s + fc2b[c];
    }
    __syncthreads();

    if (tid < 16) {
        int m = tid;
        float mx = -1e30f;
        #pragma unroll
        for (int c = 0; c < 10; ++c) mx = fmaxf(mx, s_lg[m * 10 + c]);
        float sum = 0.f;
        #pragma unroll
        for (int c = 0; c < 10; ++c) sum += expf(s_lg[m * 10 + c] - mx);
        float lse = mx + logf(sum);
        #pragma unroll
        for (int c = 0; c < 10; ++c)
            out[(size_t)(mBase + m) * 10 + c] = s_lg[m * 10 + c] - lse;
    }
}

extern "C" void kernel_launch(void* const* d_in, const int* in_sizes, int n_in,
                              void* d_out, int out_size, void* d_ws, size_t ws_size,
                              hipStream_t stream) {
    const float* x    = (const float*)d_in[0];
    const int*   hi1  = (const int*)d_in[1];
    const int*   hi2  = (const int*)d_in[2];
    const int*   hi3  = (const int*)d_in[3];
    const float* s1   = (const float*)d_in[4];
    const float* s2   = (const float*)d_in[5];
    const float* s3   = (const float*)d_in[6];
    const float* w1   = (const float*)d_in[7];
    const float* b1   = (const float*)d_in[8];
    const float* w2   = (const float*)d_in[9];
    const float* b2   = (const float*)d_in[10];
    const float* w3   = (const float*)d_in[11];
    const float* b3   = (const float*)d_in[12];
    const float* fc2w = (const float*)d_in[13];
    const float* fc2b = (const float*)d_in[14];
    float* out = (float*)d_out;

    const int B = in_sizes[0] / 784;   // 4096

    char* ws = (char*)d_ws;
    __hip_bfloat16* wc1b = (__hip_bfloat16*)(ws + 0);
    __hip_bfloat16* wc2b = (__hip_bfloat16*)(ws + 2048);
    __hip_bfloat16* W3   = (__hip_bfloat16*)(ws + 104448);
    __hip_bfloat16* h2   = (__hip_bfloat16*)(ws + 1153024);

    k_reconstruct<<<(576512 + 255) / 256, 256, 0, stream>>>(
        w1, w2, w3, hi1, hi2, hi3, s1, s2, s3, wc1b, wc2b, W3);
    k_conv<<<B / 4, 512, 0, stream>>>(x, wc1b, wc2b, b1, b2, h2);
    k_fc<<<B / 16, 1024, 0, stream>>>(h2, W3, b3, fc2w, fc2b, out);
}